// Round 12
// baseline (1550.630 us; speedup 1.0000x reference)
//
#include <hip/hip_runtime.h>
#include <hip/hip_bf16.h>

// Transformer with RPQ-quantized weights, MI355X bf16 MFMA implementation.
// B=8, S=1024, DIM=1024, HEADS=16, DH=64, NQKV=3072, M=8192, DEPTH=6.

typedef __bf16 bf16x8 __attribute__((ext_vector_type(8)));
typedef __bf16 bf16x4 __attribute__((ext_vector_type(4)));
typedef float  f32x4  __attribute__((ext_vector_type(4)));
typedef float  f32x16 __attribute__((ext_vector_type(16)));
typedef unsigned int u32x4 __attribute__((ext_vector_type(4)));
typedef unsigned int u32_as1 __attribute__((address_space(1)));
typedef unsigned int u32_as3 __attribute__((address_space(3)));

#define MFMA16(a, b, c) __builtin_amdgcn_mfma_f32_16x16x32_bf16(a, b, c, 0, 0, 0)
#define MFMA32(a, b, c) __builtin_amdgcn_mfma_f32_32x32x16_bf16(a, b, c, 0, 0, 0)

__device__ __forceinline__ void gload16(void* lds, const void* g) {
  // LDS dest = wave-uniform base + lane*16 (linear). Global src is per-lane.
  __builtin_amdgcn_global_load_lds((u32_as1*)(void*)g, (u32_as3*)lds, 16, 0, 0);
}

// v_cvt_pk_bf16_f32: one instr packs two f32 -> two bf16 in a dword (T12 recipe).
__device__ __forceinline__ unsigned pack2(float a, float b) {
  unsigned r;
  asm("v_cvt_pk_bf16_f32 %0, %1, %2" : "=v"(r) : "v"(a), "v"(b));
  return r;
}
// v_permlane32_swap_b32: a.lanes[32:63] <-> b.lanes[0:31].
__device__ __forceinline__ void pswap(unsigned& a, unsigned& b) {
  asm("v_permlane32_swap_b32 %0, %1" : "+v"(a), "+v"(b));
}
__device__ __forceinline__ float max3f(float a, float b, float c) {
  return fmaxf(fmaxf(a, b), c);   // clang fuses to v_max3_f32
}

// ---------------- fused dequant + LN1 ----------------
// blocks 0..6143: W[r][g*64+j] = cb[g][codes[r][g]][j]  (bf16)
// blocks 6144..14335: row-layernorm of lnsrc (fp32) -> bf16 lnout
__global__ __launch_bounds__(256) void deq_ln_kernel(
    __bf16* __restrict__ W,
    const float* __restrict__ cb0, const float* __restrict__ cb1,
    const float* __restrict__ cb2, const float* __restrict__ cb3,
    const int* __restrict__ codes_qkv, const int* __restrict__ codes_out,
    const int* __restrict__ codes_fc1, const int* __restrict__ codes_fc2,
    const float* __restrict__ lnsrc, const float* __restrict__ lnw,
    const float* __restrict__ lnb, __bf16* __restrict__ lnout)
{
  const int t = threadIdx.x;
  if (blockIdx.x < 6144) {
    const int r = blockIdx.x;    // qkv 3072 | out 1024 | fc1 1024 | fc2 1024
    const float* cb; const int* cr;
    if (r < 3072)      { cb = cb0; cr = codes_qkv + r * 16; }
    else if (r < 4096) { cb = cb1; cr = codes_out + (r - 3072) * 16; }
    else if (r < 5120) { cb = cb2; cr = codes_fc1 + (r - 4096) * 16; }
    else               { cb = cb3; cr = codes_fc2 + (r - 5120) * 16; }
    const int g = t >> 4, j = (t & 15) * 4;
    const int code = cr[g];
    const float4 v = *(const float4*)(cb + ((size_t)(g * 256 + code) * 64) + j);
    bf16x4 o = { (__bf16)v.x, (__bf16)v.y, (__bf16)v.z, (__bf16)v.w };
    *(bf16x4*)(W + (size_t)r * 1024 + g * 64 + j) = o;
    return;
  }
  const int row = blockIdx.x - 6144;
  const float4 v = *(const float4*)(lnsrc + (size_t)row * 1024 + t * 4);
  float s  = v.x + v.y + v.z + v.w;
  float sq = v.x * v.x + v.y * v.y + v.z * v.z + v.w * v.w;
  #pragma unroll
  for (int off = 32; off > 0; off >>= 1) {
    s  += __shfl_xor(s,  off, 64);
    sq += __shfl_xor(sq, off, 64);
  }
  __shared__ float red[8];
  const int wid = t >> 6, lane = t & 63;
  if (lane == 0) { red[wid] = s; red[4 + wid] = sq; }
  __syncthreads();
  s  = red[0] + red[1] + red[2] + red[3];
  sq = red[4] + red[5] + red[6] + red[7];
  const float mean = s * (1.0f / 1024.0f);
  const float var  = sq * (1.0f / 1024.0f) - mean * mean;
  const float rstd = rsqrtf(var + 1e-5f);
  const float4 wv = *(const float4*)(lnw + t * 4);
  const float4 bv = *(const float4*)(lnb + t * 4);
  bf16x4 o = { (__bf16)((v.x - mean) * rstd * wv.x + bv.x),
               (__bf16)((v.y - mean) * rstd * wv.y + bv.y),
               (__bf16)((v.z - mean) * rstd * wv.z + bv.z),
               (__bf16)((v.w - mean) * rstd * wv.w + bv.w) };
  *(bf16x4*)(lnout + (size_t)row * 1024 + t * 4) = o;
}

// ---------------- layernorm (standalone, for LN2) ----------------
__global__ __launch_bounds__(256) void ln_kernel(
    const float* __restrict__ x, const float* __restrict__ w,
    const float* __restrict__ b, __bf16* __restrict__ out)
{
  const int row = blockIdx.x, t = threadIdx.x;
  const float4 v = *(const float4*)(x + (size_t)row * 1024 + t * 4);
  float s  = v.x + v.y + v.z + v.w;
  float sq = v.x * v.x + v.y * v.y + v.z * v.z + v.w * v.w;
  #pragma unroll
  for (int off = 32; off > 0; off >>= 1) {
    s  += __shfl_xor(s,  off, 64);
    sq += __shfl_xor(sq, off, 64);
  }
  __shared__ float red[8];
  const int wid = t >> 6, lane = t & 63;
  if (lane == 0) { red[wid] = s; red[4 + wid] = sq; }
  __syncthreads();
  s  = red[0] + red[1] + red[2] + red[3];
  sq = red[4] + red[5] + red[6] + red[7];
  const float mean = s * (1.0f / 1024.0f);
  const float var  = sq * (1.0f / 1024.0f) - mean * mean;
  const float rstd = rsqrtf(var + 1e-5f);
  const float4 wv = *(const float4*)(w + t * 4);
  const float4 bv = *(const float4*)(b + t * 4);
  bf16x4 o = { (__bf16)((v.x - mean) * rstd * wv.x + bv.x),
               (__bf16)((v.y - mean) * rstd * wv.y + bv.y),
               (__bf16)((v.z - mean) * rstd * wv.z + bv.z),
               (__bf16)((v.w - mean) * rstd * wv.w + bv.w) };
  *(bf16x4*)(out + (size_t)row * 1024 + t * 4) = o;
}

// ---------------- GEMM: C[M=8192, N] = A[M,1024] * Bw[N,1024]^T, m97-style ----------------
// Round-8 proven structure: 128x128 tile, BK=32, 16KB LDS, stage->sync->compute->sync,
// 16x16x32 MFMA.
// EPI 0: scatter qkv -> Q/K (B,H,S,D), VT (B,H,D,S)
// EPI 1: oX = oXin + v + bias   (fp32 residual; in/out may alias)
// EPI 2: H = bf16(gelu(v + bias))
template<int EPI>
__global__ __launch_bounds__(256) void gemm_kernel(
    const __bf16* __restrict__ A, const __bf16* __restrict__ Bw,
    __bf16* __restrict__ oQ, __bf16* __restrict__ oK, __bf16* __restrict__ oVT,
    __bf16* __restrict__ oH, float* __restrict__ oX, const float* __restrict__ oXin,
    const float* __restrict__ bias)
{
  __shared__ char smem[16384] __attribute__((aligned(128)));  // A 8KB | B 8KB
  const int tid  = threadIdx.x;
  const int lane = tid & 63, wid = tid >> 6;
  const int l15 = lane & 15, l4 = lane >> 4;
  const int wr = wid >> 1, wc = wid & 1;          // 2x2 waves, 64x64 each
  const int m0 = blockIdx.x * 128, n0 = blockIdx.y * 128;

  const int srow = tid >> 2;            // staging row 0..63
  const int scol = (tid & 3) * 8;       // staging col 0,8,16,24

  f32x4 acc[4][4];
  #pragma unroll
  for (int i = 0; i < 4; ++i)
    #pragma unroll
    for (int j = 0; j < 4; ++j) acc[i][j] = (f32x4){0.f, 0.f, 0.f, 0.f};

  const __bf16* gA = A  + (size_t)(m0 + srow) * 1024 + scol;
  const __bf16* gB = Bw + (size_t)(n0 + srow) * 1024 + scol;
  char* ldsA0 = smem + wid * 1024;
  char* ldsA1 = smem + 4096  + wid * 1024;
  char* ldsB0 = smem + 8192  + wid * 1024;
  char* ldsB1 = smem + 12288 + wid * 1024;
  const int aoff = l15 * 64 + l4 * 16;  // frag byte offset within row-block (ld=32 elems)

  for (int kk = 0; kk < 32; ++kk) {
    const int kb = kk * 32;
    gload16(ldsA0, gA + kb);
    gload16(ldsA1, gA + 64 * 1024 + kb);
    gload16(ldsB0, gB + kb);
    gload16(ldsB1, gB + 64 * 1024 + kb);
    __syncthreads();   // drains vmcnt -> LDS tiles ready
    bf16x8 af[4], bfr[4];
    #pragma unroll
    for (int mi = 0; mi < 4; ++mi)
      af[mi] = *(const bf16x8*)(smem + (wr * 64 + mi * 16) * 64 + aoff);
    #pragma unroll
    for (int ni = 0; ni < 4; ++ni)
      bfr[ni] = *(const bf16x8*)(smem + 8192 + (wc * 64 + ni * 16) * 64 + aoff);
    #pragma unroll
    for (int mi = 0; mi < 4; ++mi)
      #pragma unroll
      for (int ni = 0; ni < 4; ++ni)
        acc[mi][ni] = MFMA16(af[mi], bfr[ni], acc[mi][ni]);
    __syncthreads();   // protect LDS before next overwrite
  }

  #pragma unroll
  for (int mi = 0; mi < 4; ++mi) {
    #pragma unroll
    for (int ni = 0; ni < 4; ++ni) {
      const int n = n0 + wc * 64 + ni * 16 + l15;
      if constexpr (EPI == 0) {
        const int region = n >> 10, nn = n & 1023;
        const int hh = nn >> 6, d = nn & 63;
        const int m_base = m0 + wr * 64 + mi * 16 + l4 * 4;
        const int bb = m_base >> 10, s = m_base & 1023;
        if (region == 2) {
          // packed bf16x4 store: 4 consecutive s at fixed d
          bf16x4 pv = { (__bf16)acc[mi][ni][0], (__bf16)acc[mi][ni][1],
                        (__bf16)acc[mi][ni][2], (__bf16)acc[mi][ni][3] };
          *(bf16x4*)(oVT + ((size_t)(bb * 16 + hh) * 64 + d) * 1024 + s) = pv;
        } else {
          #pragma unroll
          for (int r = 0; r < 4; ++r) {
            const __bf16 bv = (__bf16)acc[mi][ni][r];
            if (region == 0) oQ[((size_t)(bb * 16 + hh) * 1024 + s + r) * 64 + d] = bv;
            else             oK[((size_t)(bb * 16 + hh) * 1024 + s + r) * 64 + d] = bv;
          }
        }
      } else {
        #pragma unroll
        for (int r = 0; r < 4; ++r) {
          const int m = m0 + wr * 64 + mi * 16 + l4 * 4 + r;
          const float v = acc[mi][ni][r];
          if constexpr (EPI == 1) {
            oX[(size_t)m * 1024 + n] = oXin[(size_t)m * 1024 + n] + v + bias[n];
          } else {
            float t = v + bias[n];
            t = 0.5f * t * (1.0f + erff(t * 0.70710678118f));
            oH[(size_t)m * 1024 + n] = (__bf16)t;
          }
        }
      }
    }
  }
}

// ---------------- flash attention, LDS-staged K/V, swapped-QK in-register softmax ----------
// Q,K (B,H,S,D) bf16, VT (B,H,D,S) bf16 -> AO (B,S,H*D) bf16.
// r12: 4 waves x 32 q = 128 q rows per block, grid = 8 qt x 128 bh = 1024 blocks
// (4 blocks/CU, same 16 waves/CU as r8 but 4 independent barrier domains -> staging of
// one block overlaps compute of others). Per kt the BLOCK stages K[64][64] + V(T)[64][64]
// (16KB) into double-buffered LDS with 16 coalesced global_load_lds_dwordx4 (4 per wave),
// prefetched one kt ahead. LDS linear (rule 21); swizzle f(row)=(row&7)^((row>>3)&3)
// applied on the GLOBAL source slot and on ds_read (invariant: (chunk+4)&3 == chunk&3).
// VALU trims: persistent zero C-vector for QK^T; v_cvt_pk_bf16_f32 for P-packing.
__global__ __launch_bounds__(256, 4) void attn_kernel(
    const __bf16* __restrict__ Q, const __bf16* __restrict__ K,
    const __bf16* __restrict__ VT, __bf16* __restrict__ AO)
{
  const int bh = blockIdx.x & 127;      // (b*16 + h)
  const int qt = blockIdx.x >> 7;       // 0..7
  const int tid = threadIdx.x, lane = tid & 63, wid = tid >> 6;   // 4 waves
  const int l31 = lane & 31, hi = lane >> 5;
  const int q0 = qt * 128 + wid * 32;

  const __bf16* Qb = Q  + (size_t)bh * 65536;
  const __bf16* Kb = K  + (size_t)bh * 65536;
  const __bf16* Vb = VT + (size_t)bh * 65536;

  __shared__ char lds[2][16384] __attribute__((aligned(128)));  // [buf][K 8KB | V 8KB]

  const float ascale = 0.125f * 1.44269504089f;  // SCALE * log2(e)

  const int srow_in_chunk = lane >> 3;                                   // 0..7
  const int scol = (((lane & 7) ^ srow_in_chunk ^ (wid & 3)) << 3);      // elems

  // wave wid stages K chunks {wid, wid+4} and V chunks {wid, wid+4}
  #define STAGE(buf, kb_)                                                              \
    {                                                                                  \
      const int row0 = wid * 8 + srow_in_chunk;                                        \
      const int row1 = (wid + 4) * 8 + srow_in_chunk;                                  \
      gload16((buf) + wid * 1024,              Kb + (size_t)((kb_) + row0) * 64 + scol); \
      gload16((buf) + (wid + 4) * 1024,        Kb + (size_t)((kb_) + row1) * 64 + scol); \
      gload16((buf) + 8192 + wid * 1024,       Vb + (size_t)row0 * 1024 + (kb_) + scol); \
      gload16((buf) + 8192 + (wid + 4) * 1024, Vb + (size_t)row1 * 1024 + (kb_) + scol); \
    }

  bf16x8 qf[4];
  #pragma unroll
  for (int c = 0; c < 4; ++c)
    qf[c] = *(const bf16x8*)(Qb + (size_t)(q0 + l31) * 64 + c * 16 + hi * 8);

  // ones B-frag for the row-sum MFMA; persistent zero C-vector for QK^T
  const u32x4 onesu = { 0x3f803f80u, 0x3f803f80u, 0x3f803f80u, 0x3f803f80u };
  const bf16x8 ones = __builtin_bit_cast(bf16x8, onesu);
  f32x16 zv;
  #pragma unroll
  for (int r = 0; r < 16; ++r) zv[r] = 0.f;

  f32x16 o0, o1, sacc;
  #pragma unroll
  for (int r = 0; r < 16; ++r) { o0[r] = 0.f; o1[r] = 0.f; sacc[r] = 0.f; }
  float m = -1e30f;

  const int swz = (((l31 & 7) ^ ((l31 >> 3) & 3)) << 4);   // ds_read swizzle bytes

  STAGE(lds[0], 0);

  for (int kt = 0; kt < 16; ++kt) {
    __syncthreads();   // implicit vmcnt(0): this kt's staged tiles landed; prev readers done
    const char* Kl = lds[kt & 1];
    const char* Vl = lds[kt & 1] + 8192;
    if (kt < 15) STAGE(lds[(kt + 1) & 1], (kt + 1) * 64);   // in flight across compute

    f32x16 s0, s1;
    __builtin_amdgcn_s_setprio(1);
    {
      bf16x8 kf0 = *(const bf16x8*)(Kl + l31 * 128        + ((hi * 16) ^ swz));
      bf16x8 kf1 = *(const bf16x8*)(Kl + (32 + l31) * 128 + ((hi * 16) ^ swz));
      s0 = MFMA32(kf0, qf[0], zv);   // S[k][q]: row=k, col=q=lane&31
      s1 = MFMA32(kf1, qf[0], zv);
    }
    #pragma unroll
    for (int c = 1; c < 4; ++c) {
      bf16x8 kf0 = *(const bf16x8*)(Kl + l31 * 128        + ((c * 32 + hi * 16) ^ swz));
      bf16x8 kf1 = *(const bf16x8*)(Kl + (32 + l31) * 128 + ((c * 32 + hi * 16) ^ swz));
      s0 = MFMA32(kf0, qf[c], s0);
      s1 = MFMA32(kf1, qf[c], s1);
    }
    __builtin_amdgcn_s_setprio(0);
    // full 64-k row max for this lane's q: max3-shaped tree (v_max3_f32, T17)
    float p0 = max3f(s0[0],  s0[1],  s0[2]);
    float p1 = max3f(s0[3],  s0[4],  s0[5]);
    float p2 = max3f(s0[6],  s0[7],  s0[8]);
    float p3 = max3f(s0[9],  s0[10], s0[11]);
    float p4 = max3f(s0[12], s0[13], s0[14]);
    float q1_ = max3f(s1[0],  s1[1],  s1[2]);
    float q2_ = max3f(s1[3],  s1[4],  s1[5]);
    float q3_ = max3f(s1[6],  s1[7],  s1[8]);
    float q4_ = max3f(s1[9],  s1[10], s1[11]);
    float q5_ = max3f(s1[12], s1[13], s1[14]);
    float ta = max3f(p0, p1, p2);
    float tb = max3f(p3, p4, s0[15]);
    float tc = max3f(q1_, q2_, q3_);
    float td = max3f(q4_, q5_, s1[15]);
    float pm = fmaxf(fmaxf(ta, tb), fmaxf(tc, td));
    pm = fmaxf(pm, __shfl_xor(pm, 32, 64));
    const float pmx = pm * ascale;
    if (__any((int)(pmx > m + 8.0f))) {    // rare: rescale path
      const float mnew = fmaxf(m, pmx);
      const float a = exp2f(m - mnew);
      m = mnew;
      #pragma unroll
      for (int r = 0; r < 16; ++r) {
        const float ab = __shfl(a, (r & 3) + 8 * (r >> 2) + 4 * hi, 64);
        o0[r] *= ab; o1[r] *= ab; sacc[r] *= ab;
      }
    }
    const float nm = -m;
    #pragma unroll
    for (int r = 0; r < 16; ++r) {
      s0[r] = exp2f(fmaf(s0[r], ascale, nm));
      s1[r] = exp2f(fmaf(s1[r], ascale, nm));
    }
    // in-register P -> A-frag redistribution (v_cvt_pk_bf16_f32 + permlane32_swap)
    unsigned a0 = pack2(s0[0], s0[1]),   b0 = pack2(s0[4], s0[5]);
    unsigned a1 = pack2(s0[2], s0[3]),   b1 = pack2(s0[6], s0[7]);
    unsigned a2 = pack2(s0[8], s0[9]),   b2 = pack2(s0[12], s0[13]);
    unsigned a3 = pack2(s0[10], s0[11]), b3 = pack2(s0[14], s0[15]);
    unsigned c0 = pack2(s1[0], s1[1]),   d0 = pack2(s1[4], s1[5]);
    unsigned c1 = pack2(s1[2], s1[3]),   d1 = pack2(s1[6], s1[7]);
    unsigned c2 = pack2(s1[8], s1[9]),   d2 = pack2(s1[12], s1[13]);
    unsigned c3 = pack2(s1[10], s1[11]), d3 = pack2(s1[14], s1[15]);
    pswap(a0, b0); pswap(a1, b1); pswap(a2, b2); pswap(a3, b3);
    pswap(c0, d0); pswap(c1, d1); pswap(c2, d2); pswap(c3, d3);
    bf16x8 pfrag[4];
    pfrag[0] = __builtin_bit_cast(bf16x8, (u32x4){a0, a1, b0, b1});
    pfrag[1] = __builtin_bit_cast(bf16x8, (u32x4){a2, a3, b2, b3});
    pfrag[2] = __builtin_bit_cast(bf16x8, (u32x4){c0, c1, d0, d1});
    pfrag[3] = __builtin_bit_cast(bf16x8, (u32x4){c2, c3, d2, d3});
    // PV + row-sum from LDS V tile (same swizzle); sacc layout == o layout
    __builtin_amdgcn_s_setprio(1);
    #pragma unroll
    for (int c = 0; c < 4; ++c) {
      bf16x8 v0 = *(const bf16x8*)(Vl + l31 * 128        + ((c * 32 + hi * 16) ^ swz));
      bf16x8 v1 = *(const bf16x8*)(Vl + (32 + l31) * 128 + ((c * 32 + hi * 16) ^ swz));
      o0 = MFMA32(pfrag[c], v0, o0);
      o1 = MFMA32(pfrag[c], v1, o1);
      sacc = MFMA32(pfrag[c], ones, sacc);
    }
    __builtin_amdgcn_s_setprio(0);
  }
  #undef STAGE

  const int bb = bh >> 4, hh = bh & 15;
  #pragma unroll
  for (int r = 0; r < 16; ++r) {
    const int crow = (r & 3) + 8 * (r >> 2) + 4 * hi;
    const float lb = 1.0f / sacc[r];
    const int srow = q0 + crow;
    AO[(size_t)(bb * 1024 + srow) * 1024 + hh * 64 + l31]      = (__bf16)(o0[r] * lb);
    AO[(size_t)(bb * 1024 + srow) * 1024 + hh * 64 + 32 + l31] = (__bf16)(o1[r] * lb);
  }
}

// ---------------- launch ----------------
extern "C" void kernel_launch(void* const* d_in, const int* in_sizes, int n_in,
                              void* d_out, int out_size, void* d_ws, size_t ws_size,
                              hipStream_t stream)
{
  const float* x        = (const float*)d_in[0];
  const float* cb0      = (const float*)d_in[1];
  const float* cb1      = (const float*)d_in[2];
  const float* cb2      = (const float*)d_in[3];
  const float* cb3      = (const float*)d_in[4];
  const int* codes_qkv  = (const int*)d_in[5];
  const int* codes_out  = (const int*)d_in[6];
  const int* codes_fc1  = (const int*)d_in[7];
  const int* codes_fc2  = (const int*)d_in[8];
  const float* b_out    = (const float*)d_in[9];
  const float* b_fc1    = (const float*)d_in[10];
  const float* b_fc2    = (const float*)d_in[11];
  const float* ln1_w    = (const float*)d_in[12];
  const float* ln1_b    = (const float*)d_in[13];
  const float* ln2_w    = (const float*)d_in[14];
  const float* ln2_b    = (const float*)d_in[15];

  float* X = (float*)d_out;              // residual stream lives here (fp32)
  __bf16* ws = (__bf16*)d_ws;
  __bf16* W  = ws;                       // 6144x1024
  __bf16* xn = ws + 6291456;             // 8192x1024
  __bf16* Qb = ws + 14680064;            // (B,H,S,D)
  __bf16* Kb = ws + 23068672;            // (B,H,S,D)
  __bf16* VT = ws + 31457280;            // (B,H,D,S)
  __bf16* AO = ws + 39845888;            // 8192x1024
  __bf16* Hb = ws + 48234496;            // 8192x1024

  for (int i = 0; i < 6; ++i) {
    // layer 0 reads the original input x directly (no X-init memcpy needed)
    const float* Xsrc = (i == 0) ? x : X;

    deq_ln_kernel<<<14336, 256, 0, stream>>>(
        W, cb0, cb1, cb2, cb3,
        codes_qkv + (size_t)i * 3072 * 16, codes_out + (size_t)i * 1024 * 16,
        codes_fc1 + (size_t)i * 1024 * 16, codes_fc2 + (size_t)i * 1024 * 16,
        Xsrc, ln1_w + i * 1024, ln1_b + i * 1024, xn);

    gemm_kernel<0><<<dim3(64, 24), 256, 0, stream>>>(
        xn, W, Qb, Kb, VT, nullptr, nullptr, nullptr, nullptr);

    attn_kernel<<<1024, 256, 0, stream>>>(Qb, Kb, VT, AO);

    gemm_kernel<1><<<dim3(64, 8), 256, 0, stream>>>(
        AO, W + (size_t)3072 * 1024, nullptr, nullptr, nullptr, nullptr, X, Xsrc,
        b_out + i * 1024);

    ln_kernel<<<8192, 256, 0, stream>>>(X, ln2_w + i * 1024, ln2_b + i * 1024, xn);

    gemm_kernel<2><<<dim3(64, 8), 256, 0, stream>>>(
        xn, W + (size_t)4096 * 1024, nullptr, nullptr, nullptr, Hb, nullptr, nullptr,
        b_fc1 + i * 1024);

    gemm_kernel<1><<<dim3(64, 8), 256, 0, stream>>>(
        Hb, W + (size_t)5120 * 1024, nullptr, nullptr, nullptr, nullptr, X, X,
        b_fc2 + i * 1024);
  }
}

// Round 13
// 1450.570 us; speedup vs baseline: 1.0690x; 1.0690x over previous
//
#include <hip/hip_runtime.h>
#include <hip/hip_bf16.h>

// Transformer with RPQ-quantized weights, MI355X bf16 MFMA implementation.
// B=8, S=1024, DIM=1024, HEADS=16, DH=64, NQKV=3072, M=8192, DEPTH=6.
// Round-13: byte-exact restoration of the round-8 empirical optimum (1446 us).

typedef __bf16 bf16x8 __attribute__((ext_vector_type(8)));
typedef __bf16 bf16x4 __attribute__((ext_vector_type(4)));
typedef float  f32x4  __attribute__((ext_vector_type(4)));
typedef float  f32x16 __attribute__((ext_vector_type(16)));
typedef unsigned int u32x4 __attribute__((ext_vector_type(4)));
typedef unsigned int u32_as1 __attribute__((address_space(1)));
typedef unsigned int u32_as3 __attribute__((address_space(3)));

#define MFMA16(a, b, c) __builtin_amdgcn_mfma_f32_16x16x32_bf16(a, b, c, 0, 0, 0)
#define MFMA32(a, b, c) __builtin_amdgcn_mfma_f32_32x32x16_bf16(a, b, c, 0, 0, 0)

__device__ __forceinline__ void gload16(void* lds, const void* g) {
  // LDS dest = wave-uniform base + lane*16 (linear). Global src is per-lane.
  __builtin_amdgcn_global_load_lds((u32_as1*)(void*)g, (u32_as3*)lds, 16, 0, 0);
}

// v_cvt_pk_bf16_f32: one instr packs two f32 -> two bf16 in a dword (T12 recipe).
__device__ __forceinline__ unsigned pack2(float a, float b) {
  unsigned r;
  asm("v_cvt_pk_bf16_f32 %0, %1, %2" : "=v"(r) : "v"(a), "v"(b));
  return r;
}
// v_permlane32_swap_b32: a.lanes[32:63] <-> b.lanes[0:31].
__device__ __forceinline__ void pswap(unsigned& a, unsigned& b) {
  asm("v_permlane32_swap_b32 %0, %1" : "+v"(a), "+v"(b));
}
__device__ __forceinline__ float max3f(float a, float b, float c) {
  return fmaxf(fmaxf(a, b), c);   // clang fuses to v_max3_f32
}

// ---------------- fused dequant + LN1 ----------------
// blocks 0..6143: W[r][g*64+j] = cb[g][codes[r][g]][j]  (bf16)
// blocks 6144..14335: row-layernorm of lnsrc (fp32) -> bf16 lnout
__global__ __launch_bounds__(256) void deq_ln_kernel(
    __bf16* __restrict__ W,
    const float* __restrict__ cb0, const float* __restrict__ cb1,
    const float* __restrict__ cb2, const float* __restrict__ cb3,
    const int* __restrict__ codes_qkv, const int* __restrict__ codes_out,
    const int* __restrict__ codes_fc1, const int* __restrict__ codes_fc2,
    const float* __restrict__ lnsrc, const float* __restrict__ lnw,
    const float* __restrict__ lnb, __bf16* __restrict__ lnout)
{
  const int t = threadIdx.x;
  if (blockIdx.x < 6144) {
    const int r = blockIdx.x;    // qkv 3072 | out 1024 | fc1 1024 | fc2 1024
    const float* cb; const int* cr;
    if (r < 3072)      { cb = cb0; cr = codes_qkv + r * 16; }
    else if (r < 4096) { cb = cb1; cr = codes_out + (r - 3072) * 16; }
    else if (r < 5120) { cb = cb2; cr = codes_fc1 + (r - 4096) * 16; }
    else               { cb = cb3; cr = codes_fc2 + (r - 5120) * 16; }
    const int g = t >> 4, j = (t & 15) * 4;
    const int code = cr[g];
    const float4 v = *(const float4*)(cb + ((size_t)(g * 256 + code) * 64) + j);
    bf16x4 o = { (__bf16)v.x, (__bf16)v.y, (__bf16)v.z, (__bf16)v.w };
    *(bf16x4*)(W + (size_t)r * 1024 + g * 64 + j) = o;
    return;
  }
  const int row = blockIdx.x - 6144;
  const float4 v = *(const float4*)(lnsrc + (size_t)row * 1024 + t * 4);
  float s  = v.x + v.y + v.z + v.w;
  float sq = v.x * v.x + v.y * v.y + v.z * v.z + v.w * v.w;
  #pragma unroll
  for (int off = 32; off > 0; off >>= 1) {
    s  += __shfl_xor(s,  off, 64);
    sq += __shfl_xor(sq, off, 64);
  }
  __shared__ float red[8];
  const int wid = t >> 6, lane = t & 63;
  if (lane == 0) { red[wid] = s; red[4 + wid] = sq; }
  __syncthreads();
  s  = red[0] + red[1] + red[2] + red[3];
  sq = red[4] + red[5] + red[6] + red[7];
  const float mean = s * (1.0f / 1024.0f);
  const float var  = sq * (1.0f / 1024.0f) - mean * mean;
  const float rstd = rsqrtf(var + 1e-5f);
  const float4 wv = *(const float4*)(lnw + t * 4);
  const float4 bv = *(const float4*)(lnb + t * 4);
  bf16x4 o = { (__bf16)((v.x - mean) * rstd * wv.x + bv.x),
               (__bf16)((v.y - mean) * rstd * wv.y + bv.y),
               (__bf16)((v.z - mean) * rstd * wv.z + bv.z),
               (__bf16)((v.w - mean) * rstd * wv.w + bv.w) };
  *(bf16x4*)(lnout + (size_t)row * 1024 + t * 4) = o;
}

// ---------------- layernorm (standalone, for LN2) ----------------
__global__ __launch_bounds__(256) void ln_kernel(
    const float* __restrict__ x, const float* __restrict__ w,
    const float* __restrict__ b, __bf16* __restrict__ out)
{
  const int row = blockIdx.x, t = threadIdx.x;
  const float4 v = *(const float4*)(x + (size_t)row * 1024 + t * 4);
  float s  = v.x + v.y + v.z + v.w;
  float sq = v.x * v.x + v.y * v.y + v.z * v.z + v.w * v.w;
  #pragma unroll
  for (int off = 32; off > 0; off >>= 1) {
    s  += __shfl_xor(s,  off, 64);
    sq += __shfl_xor(sq, off, 64);
  }
  __shared__ float red[8];
  const int wid = t >> 6, lane = t & 63;
  if (lane == 0) { red[wid] = s; red[4 + wid] = sq; }
  __syncthreads();
  s  = red[0] + red[1] + red[2] + red[3];
  sq = red[4] + red[5] + red[6] + red[7];
  const float mean = s * (1.0f / 1024.0f);
  const float var  = sq * (1.0f / 1024.0f) - mean * mean;
  const float rstd = rsqrtf(var + 1e-5f);
  const float4 wv = *(const float4*)(w + t * 4);
  const float4 bv = *(const float4*)(b + t * 4);
  bf16x4 o = { (__bf16)((v.x - mean) * rstd * wv.x + bv.x),
               (__bf16)((v.y - mean) * rstd * wv.y + bv.y),
               (__bf16)((v.z - mean) * rstd * wv.z + bv.z),
               (__bf16)((v.w - mean) * rstd * wv.w + bv.w) };
  *(bf16x4*)(out + (size_t)row * 1024 + t * 4) = o;
}

// ---------------- GEMM: C[M=8192, N] = A[M,1024] * Bw[N,1024]^T, m97-style ----------------
// Round-4/8 proven structure: 128x128 tile, BK=32, 16KB LDS, stage->sync->compute->sync.
// 16KB LDS keeps many blocks/CU resident; cross-block TLP hides staging latency (m114).
// EPI 0: scatter qkv -> Q/K (B,H,S,D), VT (B,H,D,S)
// EPI 1: oX = oXin + v + bias   (fp32 residual; in/out may alias)
// EPI 2: H = bf16(gelu(v + bias))
template<int EPI>
__global__ __launch_bounds__(256) void gemm_kernel(
    const __bf16* __restrict__ A, const __bf16* __restrict__ Bw,
    __bf16* __restrict__ oQ, __bf16* __restrict__ oK, __bf16* __restrict__ oVT,
    __bf16* __restrict__ oH, float* __restrict__ oX, const float* __restrict__ oXin,
    const float* __restrict__ bias)
{
  __shared__ char smem[16384] __attribute__((aligned(128)));  // A 8KB | B 8KB
  const int tid  = threadIdx.x;
  const int lane = tid & 63, wid = tid >> 6;
  const int l15 = lane & 15, l4 = lane >> 4;
  const int wr = wid >> 1, wc = wid & 1;          // 2x2 waves, 64x64 each
  const int m0 = blockIdx.x * 128, n0 = blockIdx.y * 128;

  const int srow = tid >> 2;            // staging row 0..63
  const int scol = (tid & 3) * 8;       // staging col 0,8,16,24

  f32x4 acc[4][4];
  #pragma unroll
  for (int i = 0; i < 4; ++i)
    #pragma unroll
    for (int j = 0; j < 4; ++j) acc[i][j] = (f32x4){0.f, 0.f, 0.f, 0.f};

  const __bf16* gA = A  + (size_t)(m0 + srow) * 1024 + scol;
  const __bf16* gB = Bw + (size_t)(n0 + srow) * 1024 + scol;
  char* ldsA0 = smem + wid * 1024;
  char* ldsA1 = smem + 4096  + wid * 1024;
  char* ldsB0 = smem + 8192  + wid * 1024;
  char* ldsB1 = smem + 12288 + wid * 1024;
  const int aoff = l15 * 64 + l4 * 16;  // frag byte offset within row-block (ld=32 elems)

  for (int kk = 0; kk < 32; ++kk) {
    const int kb = kk * 32;
    gload16(ldsA0, gA + kb);
    gload16(ldsA1, gA + 64 * 1024 + kb);
    gload16(ldsB0, gB + kb);
    gload16(ldsB1, gB + 64 * 1024 + kb);
    __syncthreads();   // drains vmcnt -> LDS tiles ready
    bf16x8 af[4], bfr[4];
    #pragma unroll
    for (int mi = 0; mi < 4; ++mi)
      af[mi] = *(const bf16x8*)(smem + (wr * 64 + mi * 16) * 64 + aoff);
    #pragma unroll
    for (int ni = 0; ni < 4; ++ni)
      bfr[ni] = *(const bf16x8*)(smem + 8192 + (wc * 64 + ni * 16) * 64 + aoff);
    #pragma unroll
    for (int mi = 0; mi < 4; ++mi)
      #pragma unroll
      for (int ni = 0; ni < 4; ++ni)
        acc[mi][ni] = MFMA16(af[mi], bfr[ni], acc[mi][ni]);
    __syncthreads();   // protect LDS before next overwrite
  }

  #pragma unroll
  for (int mi = 0; mi < 4; ++mi) {
    #pragma unroll
    for (int ni = 0; ni < 4; ++ni) {
      const int n = n0 + wc * 64 + ni * 16 + l15;
      if constexpr (EPI == 0) {
        const int region = n >> 10, nn = n & 1023;
        const int hh = nn >> 6, d = nn & 63;
        const int m_base = m0 + wr * 64 + mi * 16 + l4 * 4;
        const int bb = m_base >> 10, s = m_base & 1023;
        if (region == 2) {
          // packed bf16x4 store: 4 consecutive s at fixed d
          bf16x4 pv = { (__bf16)acc[mi][ni][0], (__bf16)acc[mi][ni][1],
                        (__bf16)acc[mi][ni][2], (__bf16)acc[mi][ni][3] };
          *(bf16x4*)(oVT + ((size_t)(bb * 16 + hh) * 64 + d) * 1024 + s) = pv;
        } else {
          #pragma unroll
          for (int r = 0; r < 4; ++r) {
            const __bf16 bv = (__bf16)acc[mi][ni][r];
            if (region == 0) oQ[((size_t)(bb * 16 + hh) * 1024 + s + r) * 64 + d] = bv;
            else             oK[((size_t)(bb * 16 + hh) * 1024 + s + r) * 64 + d] = bv;
          }
        }
      } else {
        #pragma unroll
        for (int r = 0; r < 4; ++r) {
          const int m = m0 + wr * 64 + mi * 16 + l4 * 4 + r;
          const float v = acc[mi][ni][r];
          if constexpr (EPI == 1) {
            oX[(size_t)m * 1024 + n] = oXin[(size_t)m * 1024 + n] + v + bias[n];
          } else {
            float t = v + bias[n];
            t = 0.5f * t * (1.0f + erff(t * 0.70710678118f));
            oH[(size_t)m * 1024 + n] = (__bf16)t;
          }
        }
      }
    }
  }
}

// ---------------- flash attention, LDS-staged K/V, swapped-QK in-register softmax ----------
// Q,K (B,H,S,D) bf16, VT (B,H,D,S) bf16 -> AO (B,S,H*D) bf16.
// grid = qt*128 + bh (512 blocks); 8 waves x 32 q = 256 q rows per block.
// Per kt the BLOCK stages K[64][64] + V(T)[64][64] (16KB) into double-buffered LDS with
// 16 coalesced global_load_lds_dwordx4 (2 per wave), prefetched one kt ahead.
// LDS is linear (gload_lds rule 21); swizzle applied on GLOBAL source slot and on ds_read.
// VALU trims: persistent zero C-vector for QK^T; v_cvt_pk_bf16_f32 for P-packing.
__global__ __launch_bounds__(512, 4) void attn_kernel(
    const __bf16* __restrict__ Q, const __bf16* __restrict__ K,
    const __bf16* __restrict__ VT, __bf16* __restrict__ AO)
{
  const int bh = blockIdx.x & 127;      // (b*16 + h)
  const int qt = blockIdx.x >> 7;       // 0..3
  const int tid = threadIdx.x, lane = tid & 63, wid = tid >> 6;   // 8 waves
  const int l31 = lane & 31, hi = lane >> 5;
  const int q0 = qt * 256 + wid * 32;

  const __bf16* Qb = Q  + (size_t)bh * 65536;
  const __bf16* Kb = K  + (size_t)bh * 65536;
  const __bf16* Vb = VT + (size_t)bh * 65536;

  __shared__ char lds[2][16384] __attribute__((aligned(128)));  // [buf][K 8KB | V 8KB]

  const float ascale = 0.125f * 1.44269504089f;  // SCALE * log2(e)

  const int srow_in_chunk = lane >> 3;                                   // 0..7
  const int scol = (((lane & 7) ^ srow_in_chunk ^ (wid & 3)) << 3);      // elems

  #define STAGE(buf, kb_)                                                       \
    {                                                                           \
      const int row_ = wid * 8 + srow_in_chunk;                                 \
      gload16((buf) + wid * 1024, Kb + (size_t)((kb_) + row_) * 64 + scol);     \
      gload16((buf) + 8192 + wid * 1024, Vb + (size_t)row_ * 1024 + (kb_) + scol); \
    }

  bf16x8 qf[4];
  #pragma unroll
  for (int c = 0; c < 4; ++c)
    qf[c] = *(const bf16x8*)(Qb + (size_t)(q0 + l31) * 64 + c * 16 + hi * 8);

  // ones B-frag for the row-sum MFMA; persistent zero C-vector for QK^T
  const u32x4 onesu = { 0x3f803f80u, 0x3f803f80u, 0x3f803f80u, 0x3f803f80u };
  const bf16x8 ones = __builtin_bit_cast(bf16x8, onesu);
  f32x16 zv;
  #pragma unroll
  for (int r = 0; r < 16; ++r) zv[r] = 0.f;

  f32x16 o0, o1, sacc;
  #pragma unroll
  for (int r = 0; r < 16; ++r) { o0[r] = 0.f; o1[r] = 0.f; sacc[r] = 0.f; }
  float m = -1e30f;

  const int swz = (((l31 & 7) ^ ((l31 >> 3) & 3)) << 4);   // ds_read swizzle bytes

  STAGE(lds[0], 0);

  for (int kt = 0; kt < 16; ++kt) {
    __syncthreads();   // implicit vmcnt(0): this kt's staged tiles landed; prev readers done
    const char* Kl = lds[kt & 1];
    const char* Vl = lds[kt & 1] + 8192;
    if (kt < 15) STAGE(lds[(kt + 1) & 1], (kt + 1) * 64);   // in flight across compute

    f32x16 s0, s1;
    __builtin_amdgcn_s_setprio(1);
    {
      bf16x8 kf0 = *(const bf16x8*)(Kl + l31 * 128        + ((hi * 16) ^ swz));
      bf16x8 kf1 = *(const bf16x8*)(Kl + (32 + l31) * 128 + ((hi * 16) ^ swz));
      s0 = MFMA32(kf0, qf[0], zv);   // S[k][q]: row=k, col=q=lane&31
      s1 = MFMA32(kf1, qf[0], zv);
    }
    #pragma unroll
    for (int c = 1; c < 4; ++c) {
      bf16x8 kf0 = *(const bf16x8*)(Kl + l31 * 128        + ((c * 32 + hi * 16) ^ swz));
      bf16x8 kf1 = *(const bf16x8*)(Kl + (32 + l31) * 128 + ((c * 32 + hi * 16) ^ swz));
      s0 = MFMA32(kf0, qf[c], s0);
      s1 = MFMA32(kf1, qf[c], s1);
    }
    __builtin_amdgcn_s_setprio(0);
    // full 64-k row max for this lane's q: max3-shaped tree (v_max3_f32, T17)
    float p0 = max3f(s0[0],  s0[1],  s0[2]);
    float p1 = max3f(s0[3],  s0[4],  s0[5]);
    float p2 = max3f(s0[6],  s0[7],  s0[8]);
    float p3 = max3f(s0[9],  s0[10], s0[11]);
    float p4 = max3f(s0[12], s0[13], s0[14]);
    float q1_ = max3f(s1[0],  s1[1],  s1[2]);
    float q2_ = max3f(s1[3],  s1[4],  s1[5]);
    float q3_ = max3f(s1[6],  s1[7],  s1[8]);
    float q4_ = max3f(s1[9],  s1[10], s1[11]);
    float q5_ = max3f(s1[12], s1[13], s1[14]);
    float ta = max3f(p0, p1, p2);
    float tb = max3f(p3, p4, s0[15]);
    float tc = max3f(q1_, q2_, q3_);
    float td = max3f(q4_, q5_, s1[15]);
    float pm = fmaxf(fmaxf(ta, tb), fmaxf(tc, td));
    pm = fmaxf(pm, __shfl_xor(pm, 32, 64));
    const float pmx = pm * ascale;
    if (__any((int)(pmx > m + 8.0f))) {    // rare: rescale path
      const float mnew = fmaxf(m, pmx);
      const float a = exp2f(m - mnew);
      m = mnew;
      #pragma unroll
      for (int r = 0; r < 16; ++r) {
        const float ab = __shfl(a, (r & 3) + 8 * (r >> 2) + 4 * hi, 64);
        o0[r] *= ab; o1[r] *= ab; sacc[r] *= ab;
      }
    }
    const float nm = -m;
    #pragma unroll
    for (int r = 0; r < 16; ++r) {
      s0[r] = exp2f(fmaf(s0[r], ascale, nm));
      s1[r] = exp2f(fmaf(s1[r], ascale, nm));
    }
    // in-register P -> A-frag redistribution (v_cvt_pk_bf16_f32 + permlane32_swap)
    unsigned a0 = pack2(s0[0], s0[1]),   b0 = pack2(s0[4], s0[5]);
    unsigned a1 = pack2(s0[2], s0[3]),   b1 = pack2(s0[6], s0[7]);
    unsigned a2 = pack2(s0[8], s0[9]),   b2 = pack2(s0[12], s0[13]);
    unsigned a3 = pack2(s0[10], s0[11]), b3 = pack2(s0[14], s0[15]);
    unsigned c0 = pack2(s1[0], s1[1]),   d0 = pack2(s1[4], s1[5]);
    unsigned c1 = pack2(s1[2], s1[3]),   d1 = pack2(s1[6], s1[7]);
    unsigned c2 = pack2(s1[8], s1[9]),   d2 = pack2(s1[12], s1[13]);
    unsigned c3 = pack2(s1[10], s1[11]), d3 = pack2(s1[14], s1[15]);
    pswap(a0, b0); pswap(a1, b1); pswap(a2, b2); pswap(a3, b3);
    pswap(c0, d0); pswap(c1, d1); pswap(c2, d2); pswap(c3, d3);
    bf16x8 pfrag[4];
    pfrag[0] = __builtin_bit_cast(bf16x8, (u32x4){a0, a1, b0, b1});
    pfrag[1] = __builtin_bit_cast(bf16x8, (u32x4){a2, a3, b2, b3});
    pfrag[2] = __builtin_bit_cast(bf16x8, (u32x4){c0, c1, d0, d1});
    pfrag[3] = __builtin_bit_cast(bf16x8, (u32x4){c2, c3, d2, d3});
    // PV + row-sum from LDS V tile (same swizzle); sacc layout == o layout
    __builtin_amdgcn_s_setprio(1);
    #pragma unroll
    for (int c = 0; c < 4; ++c) {
      bf16x8 v0 = *(const bf16x8*)(Vl + l31 * 128        + ((c * 32 + hi * 16) ^ swz));
      bf16x8 v1 = *(const bf16x8*)(Vl + (32 + l31) * 128 + ((c * 32 + hi * 16) ^ swz));
      o0 = MFMA32(pfrag[c], v0, o0);
      o1 = MFMA32(pfrag[c], v1, o1);
      sacc = MFMA32(pfrag[c], ones, sacc);
    }
    __builtin_amdgcn_s_setprio(0);
  }
  #undef STAGE

  const int bb = bh >> 4, hh = bh & 15;
  #pragma unroll
  for (int r = 0; r < 16; ++r) {
    const int crow = (r & 3) + 8 * (r >> 2) + 4 * hi;
    const float lb = 1.0f / sacc[r];
    const int srow = q0 + crow;
    AO[(size_t)(bb * 1024 + srow) * 1024 + hh * 64 + l31]      = (__bf16)(o0[r] * lb);
    AO[(size_t)(bb * 1024 + srow) * 1024 + hh * 64 + 32 + l31] = (__bf16)(o1[r] * lb);
  }
}

// ---------------- launch ----------------
extern "C" void kernel_launch(void* const* d_in, const int* in_sizes, int n_in,
                              void* d_out, int out_size, void* d_ws, size_t ws_size,
                              hipStream_t stream)
{
  const float* x        = (const float*)d_in[0];
  const float* cb0      = (const float*)d_in[1];
  const float* cb1      = (const float*)d_in[2];
  const float* cb2      = (const float*)d_in[3];
  const float* cb3      = (const float*)d_in[4];
  const int* codes_qkv  = (const int*)d_in[5];
  const int* codes_out  = (const int*)d_in[6];
  const int* codes_fc1  = (const int*)d_in[7];
  const int* codes_fc2  = (const int*)d_in[8];
  const float* b_out    = (const float*)d_in[9];
  const float* b_fc1    = (const float*)d_in[10];
  const float* b_fc2    = (const float*)d_in[11];
  const float* ln1_w    = (const float*)d_in[12];
  const float* ln1_b    = (const float*)d_in[13];
  const float* ln2_w    = (const float*)d_in[14];
  const float* ln2_b    = (const float*)d_in[15];

  float* X = (float*)d_out;              // residual stream lives here (fp32)
  __bf16* ws = (__bf16*)d_ws;
  __bf16* W  = ws;                       // 6144x1024
  __bf16* xn = ws + 6291456;             // 8192x1024
  __bf16* Qb = ws + 14680064;            // (B,H,S,D)
  __bf16* Kb = ws + 23068672;            // (B,H,S,D)
  __bf16* VT = ws + 31457280;            // (B,H,D,S)
  __bf16* AO = ws + 39845888;            // 8192x1024
  __bf16* Hb = ws + 48234496;            // 8192x1024

  for (int i = 0; i < 6; ++i) {
    // layer 0 reads the original input x directly (no X-init memcpy needed)
    const float* Xsrc = (i == 0) ? x : X;

    deq_ln_kernel<<<14336, 256, 0, stream>>>(
        W, cb0, cb1, cb2, cb3,
        codes_qkv + (size_t)i * 3072 * 16, codes_out + (size_t)i * 1024 * 16,
        codes_fc1 + (size_t)i * 1024 * 16, codes_fc2 + (size_t)i * 1024 * 16,
        Xsrc, ln1_w + i * 1024, ln1_b + i * 1024, xn);

    gemm_kernel<0><<<dim3(64, 24), 256, 0, stream>>>(
        xn, W, Qb, Kb, VT, nullptr, nullptr, nullptr, nullptr);

    attn_kernel<<<512, 512, 0, stream>>>(Qb, Kb, VT, AO);

    gemm_kernel<1><<<dim3(64, 8), 256, 0, stream>>>(
        AO, W + (size_t)3072 * 1024, nullptr, nullptr, nullptr, nullptr, X, Xsrc,
        b_out + i * 1024);

    ln_kernel<<<8192, 256, 0, stream>>>(X, ln2_w + i * 1024, ln2_b + i * 1024, xn);

    gemm_kernel<2><<<dim3(64, 8), 256, 0, stream>>>(
        xn, W + (size_t)4096 * 1024, nullptr, nullptr, nullptr, Hb, nullptr, nullptr,
        b_fc1 + i * 1024);

    gemm_kernel<1><<<dim3(64, 8), 256, 0, stream>>>(
        Hb, W + (size_t)5120 * 1024, nullptr, nullptr, nullptr, nullptr, X, X,
        b_fc2 + i * 1024);
  }
}

// Round 14
// 1397.417 us; speedup vs baseline: 1.1096x; 1.0380x over previous
//
#include <hip/hip_runtime.h>
#include <hip/hip_bf16.h>

// Transformer with RPQ-quantized weights, MI355X bf16 MFMA implementation.
// B=8, S=1024, DIM=1024, HEADS=16, DH=64, NQKV=3072, M=8192, DEPTH=6.
// Round-14: r8 structure + bf16 residual stream (X) to halve residual/LN HBM traffic.
//   - Xb (bf16) lives in ws (old Hb slot); Hb aliases AO (disjoint lifetimes).
//   - layer 0 reads fp32 x (EPI 3); final fc2 writes fp32 d_out (EPI 4).

typedef __bf16 bf16x8 __attribute__((ext_vector_type(8)));
typedef __bf16 bf16x4 __attribute__((ext_vector_type(4)));
typedef float  f32x4  __attribute__((ext_vector_type(4)));
typedef float  f32x16 __attribute__((ext_vector_type(16)));
typedef unsigned int u32x4 __attribute__((ext_vector_type(4)));
typedef unsigned int u32_as1 __attribute__((address_space(1)));
typedef unsigned int u32_as3 __attribute__((address_space(3)));

#define MFMA16(a, b, c) __builtin_amdgcn_mfma_f32_16x16x32_bf16(a, b, c, 0, 0, 0)
#define MFMA32(a, b, c) __builtin_amdgcn_mfma_f32_32x32x16_bf16(a, b, c, 0, 0, 0)

__device__ __forceinline__ void gload16(void* lds, const void* g) {
  // LDS dest = wave-uniform base + lane*16 (linear). Global src is per-lane.
  __builtin_amdgcn_global_load_lds((u32_as1*)(void*)g, (u32_as3*)lds, 16, 0, 0);
}

// v_cvt_pk_bf16_f32: one instr packs two f32 -> two bf16 in a dword (T12 recipe).
__device__ __forceinline__ unsigned pack2(float a, float b) {
  unsigned r;
  asm("v_cvt_pk_bf16_f32 %0, %1, %2" : "=v"(r) : "v"(a), "v"(b));
  return r;
}
// v_permlane32_swap_b32: a.lanes[32:63] <-> b.lanes[0:31].
__device__ __forceinline__ void pswap(unsigned& a, unsigned& b) {
  asm("v_permlane32_swap_b32 %0, %1" : "+v"(a), "+v"(b));
}
__device__ __forceinline__ float max3f(float a, float b, float c) {
  return fmaxf(fmaxf(a, b), c);   // clang fuses to v_max3_f32
}

// ---------------- fused dequant + LN1 ----------------
// blocks 0..6143: W[r][g*64+j] = cb[g][codes[r][g]][j]  (bf16)
// blocks 6144..14335: row-layernorm of lnsrc (INF32? fp32 : bf16) -> bf16 lnout
template<bool INF32>
__global__ __launch_bounds__(256) void deq_ln_kernel(
    __bf16* __restrict__ W,
    const float* __restrict__ cb0, const float* __restrict__ cb1,
    const float* __restrict__ cb2, const float* __restrict__ cb3,
    const int* __restrict__ codes_qkv, const int* __restrict__ codes_out,
    const int* __restrict__ codes_fc1, const int* __restrict__ codes_fc2,
    const void* __restrict__ lnsrc, const float* __restrict__ lnw,
    const float* __restrict__ lnb, __bf16* __restrict__ lnout)
{
  const int t = threadIdx.x;
  if (blockIdx.x < 6144) {
    const int r = blockIdx.x;    // qkv 3072 | out 1024 | fc1 1024 | fc2 1024
    const float* cb; const int* cr;
    if (r < 3072)      { cb = cb0; cr = codes_qkv + r * 16; }
    else if (r < 4096) { cb = cb1; cr = codes_out + (r - 3072) * 16; }
    else if (r < 5120) { cb = cb2; cr = codes_fc1 + (r - 4096) * 16; }
    else               { cb = cb3; cr = codes_fc2 + (r - 5120) * 16; }
    const int g = t >> 4, j = (t & 15) * 4;
    const int code = cr[g];
    const float4 v = *(const float4*)(cb + ((size_t)(g * 256 + code) * 64) + j);
    bf16x4 o = { (__bf16)v.x, (__bf16)v.y, (__bf16)v.z, (__bf16)v.w };
    *(bf16x4*)(W + (size_t)r * 1024 + g * 64 + j) = o;
    return;
  }
  const int row = blockIdx.x - 6144;
  float4 v;
  if constexpr (INF32) {
    v = *(const float4*)((const float*)lnsrc + (size_t)row * 1024 + t * 4);
  } else {
    bf16x4 bv4 = *(const bf16x4*)((const __bf16*)lnsrc + (size_t)row * 1024 + t * 4);
    v.x = (float)bv4[0]; v.y = (float)bv4[1]; v.z = (float)bv4[2]; v.w = (float)bv4[3];
  }
  float s  = v.x + v.y + v.z + v.w;
  float sq = v.x * v.x + v.y * v.y + v.z * v.z + v.w * v.w;
  #pragma unroll
  for (int off = 32; off > 0; off >>= 1) {
    s  += __shfl_xor(s,  off, 64);
    sq += __shfl_xor(sq, off, 64);
  }
  __shared__ float red[8];
  const int wid = t >> 6, lane = t & 63;
  if (lane == 0) { red[wid] = s; red[4 + wid] = sq; }
  __syncthreads();
  s  = red[0] + red[1] + red[2] + red[3];
  sq = red[4] + red[5] + red[6] + red[7];
  const float mean = s * (1.0f / 1024.0f);
  const float var  = sq * (1.0f / 1024.0f) - mean * mean;
  const float rstd = rsqrtf(var + 1e-5f);
  const float4 wv = *(const float4*)(lnw + t * 4);
  const float4 bv = *(const float4*)(lnb + t * 4);
  bf16x4 o = { (__bf16)((v.x - mean) * rstd * wv.x + bv.x),
               (__bf16)((v.y - mean) * rstd * wv.y + bv.y),
               (__bf16)((v.z - mean) * rstd * wv.z + bv.z),
               (__bf16)((v.w - mean) * rstd * wv.w + bv.w) };
  *(bf16x4*)(lnout + (size_t)row * 1024 + t * 4) = o;
}

// ---------------- layernorm (standalone, for LN2; bf16 input) ----------------
__global__ __launch_bounds__(256) void ln_kernel(
    const __bf16* __restrict__ x, const float* __restrict__ w,
    const float* __restrict__ b, __bf16* __restrict__ out)
{
  const int row = blockIdx.x, t = threadIdx.x;
  bf16x4 bv4 = *(const bf16x4*)(x + (size_t)row * 1024 + t * 4);
  float4 v;
  v.x = (float)bv4[0]; v.y = (float)bv4[1]; v.z = (float)bv4[2]; v.w = (float)bv4[3];
  float s  = v.x + v.y + v.z + v.w;
  float sq = v.x * v.x + v.y * v.y + v.z * v.z + v.w * v.w;
  #pragma unroll
  for (int off = 32; off > 0; off >>= 1) {
    s  += __shfl_xor(s,  off, 64);
    sq += __shfl_xor(sq, off, 64);
  }
  __shared__ float red[8];
  const int wid = t >> 6, lane = t & 63;
  if (lane == 0) { red[wid] = s; red[4 + wid] = sq; }
  __syncthreads();
  s  = red[0] + red[1] + red[2] + red[3];
  sq = red[4] + red[5] + red[6] + red[7];
  const float mean = s * (1.0f / 1024.0f);
  const float var  = sq * (1.0f / 1024.0f) - mean * mean;
  const float rstd = rsqrtf(var + 1e-5f);
  const float4 wv = *(const float4*)(w + t * 4);
  const float4 bv = *(const float4*)(b + t * 4);
  bf16x4 o = { (__bf16)((v.x - mean) * rstd * wv.x + bv.x),
               (__bf16)((v.y - mean) * rstd * wv.y + bv.y),
               (__bf16)((v.z - mean) * rstd * wv.z + bv.z),
               (__bf16)((v.w - mean) * rstd * wv.w + bv.w) };
  *(bf16x4*)(out + (size_t)row * 1024 + t * 4) = o;
}

// ---------------- GEMM: C[M=8192, N] = A[M,1024] * Bw[N,1024]^T, m97-style ----------------
// Round-4/8 proven structure: 128x128 tile, BK=32, 16KB LDS, stage->sync->compute->sync.
// EPI 0: scatter qkv -> Q/K (B,H,S,D), VT (B,H,D,S)
// EPI 1: Xb_out = bf16( bf16_in(Xin) + v + bias )   (residual, bf16 -> bf16)
// EPI 2: H = bf16(gelu(v + bias))
// EPI 3: Xb_out = bf16( fp32_in(Xin) + v + bias )   (layer-0 residual, fp32 -> bf16)
// EPI 4: Xf_out = fp32( bf16_in(Xin) + v + bias )   (final layer -> d_out fp32)
template<int EPI>
__global__ __launch_bounds__(256) void gemm_kernel(
    const __bf16* __restrict__ A, const __bf16* __restrict__ Bw,
    __bf16* __restrict__ oQ, __bf16* __restrict__ oK, __bf16* __restrict__ oVT,
    __bf16* __restrict__ oH, const void* __restrict__ xin, void* __restrict__ xout,
    const float* __restrict__ bias)
{
  __shared__ char smem[16384] __attribute__((aligned(128)));  // A 8KB | B 8KB
  const int tid  = threadIdx.x;
  const int lane = tid & 63, wid = tid >> 6;
  const int l15 = lane & 15, l4 = lane >> 4;
  const int wr = wid >> 1, wc = wid & 1;          // 2x2 waves, 64x64 each
  const int m0 = blockIdx.x * 128, n0 = blockIdx.y * 128;

  const int srow = tid >> 2;            // staging row 0..63
  const int scol = (tid & 3) * 8;       // staging col 0,8,16,24

  f32x4 acc[4][4];
  #pragma unroll
  for (int i = 0; i < 4; ++i)
    #pragma unroll
    for (int j = 0; j < 4; ++j) acc[i][j] = (f32x4){0.f, 0.f, 0.f, 0.f};

  const __bf16* gA = A  + (size_t)(m0 + srow) * 1024 + scol;
  const __bf16* gB = Bw + (size_t)(n0 + srow) * 1024 + scol;
  char* ldsA0 = smem + wid * 1024;
  char* ldsA1 = smem + 4096  + wid * 1024;
  char* ldsB0 = smem + 8192  + wid * 1024;
  char* ldsB1 = smem + 12288 + wid * 1024;
  const int aoff = l15 * 64 + l4 * 16;  // frag byte offset within row-block (ld=32 elems)

  for (int kk = 0; kk < 32; ++kk) {
    const int kb = kk * 32;
    gload16(ldsA0, gA + kb);
    gload16(ldsA1, gA + 64 * 1024 + kb);
    gload16(ldsB0, gB + kb);
    gload16(ldsB1, gB + 64 * 1024 + kb);
    __syncthreads();   // drains vmcnt -> LDS tiles ready
    bf16x8 af[4], bfr[4];
    #pragma unroll
    for (int mi = 0; mi < 4; ++mi)
      af[mi] = *(const bf16x8*)(smem + (wr * 64 + mi * 16) * 64 + aoff);
    #pragma unroll
    for (int ni = 0; ni < 4; ++ni)
      bfr[ni] = *(const bf16x8*)(smem + 8192 + (wc * 64 + ni * 16) * 64 + aoff);
    #pragma unroll
    for (int mi = 0; mi < 4; ++mi)
      #pragma unroll
      for (int ni = 0; ni < 4; ++ni)
        acc[mi][ni] = MFMA16(af[mi], bfr[ni], acc[mi][ni]);
    __syncthreads();   // protect LDS before next overwrite
  }

  #pragma unroll
  for (int mi = 0; mi < 4; ++mi) {
    #pragma unroll
    for (int ni = 0; ni < 4; ++ni) {
      const int n = n0 + wc * 64 + ni * 16 + l15;
      if constexpr (EPI == 0) {
        const int region = n >> 10, nn = n & 1023;
        const int hh = nn >> 6, d = nn & 63;
        const int m_base = m0 + wr * 64 + mi * 16 + l4 * 4;
        const int bb = m_base >> 10, s = m_base & 1023;
        if (region == 2) {
          // packed bf16x4 store: 4 consecutive s at fixed d
          bf16x4 pv = { (__bf16)acc[mi][ni][0], (__bf16)acc[mi][ni][1],
                        (__bf16)acc[mi][ni][2], (__bf16)acc[mi][ni][3] };
          *(bf16x4*)(oVT + ((size_t)(bb * 16 + hh) * 64 + d) * 1024 + s) = pv;
        } else {
          #pragma unroll
          for (int r = 0; r < 4; ++r) {
            const __bf16 bv = (__bf16)acc[mi][ni][r];
            if (region == 0) oQ[((size_t)(bb * 16 + hh) * 1024 + s + r) * 64 + d] = bv;
            else             oK[((size_t)(bb * 16 + hh) * 1024 + s + r) * 64 + d] = bv;
          }
        }
      } else {
        #pragma unroll
        for (int r = 0; r < 4; ++r) {
          const int m = m0 + wr * 64 + mi * 16 + l4 * 4 + r;
          const size_t idx = (size_t)m * 1024 + n;
          const float v = acc[mi][ni][r];
          if constexpr (EPI == 1) {
            const float xi = (float)((const __bf16*)xin)[idx];
            ((__bf16*)xout)[idx] = (__bf16)(xi + v + bias[n]);
          } else if constexpr (EPI == 3) {
            const float xi = ((const float*)xin)[idx];
            ((__bf16*)xout)[idx] = (__bf16)(xi + v + bias[n]);
          } else if constexpr (EPI == 4) {
            const float xi = (float)((const __bf16*)xin)[idx];
            ((float*)xout)[idx] = xi + v + bias[n];
          } else {  // EPI == 2
            float t = v + bias[n];
            t = 0.5f * t * (1.0f + erff(t * 0.70710678118f));
            oH[idx] = (__bf16)t;
          }
        }
      }
    }
  }
}

// ---------------- flash attention, LDS-staged K/V, swapped-QK in-register softmax ----------
// (byte-identical to the round-8/13 best-measured version)
__global__ __launch_bounds__(512, 4) void attn_kernel(
    const __bf16* __restrict__ Q, const __bf16* __restrict__ K,
    const __bf16* __restrict__ VT, __bf16* __restrict__ AO)
{
  const int bh = blockIdx.x & 127;      // (b*16 + h)
  const int qt = blockIdx.x >> 7;       // 0..3
  const int tid = threadIdx.x, lane = tid & 63, wid = tid >> 6;   // 8 waves
  const int l31 = lane & 31, hi = lane >> 5;
  const int q0 = qt * 256 + wid * 32;

  const __bf16* Qb = Q  + (size_t)bh * 65536;
  const __bf16* Kb = K  + (size_t)bh * 65536;
  const __bf16* Vb = VT + (size_t)bh * 65536;

  __shared__ char lds[2][16384] __attribute__((aligned(128)));  // [buf][K 8KB | V 8KB]

  const float ascale = 0.125f * 1.44269504089f;  // SCALE * log2(e)

  const int srow_in_chunk = lane >> 3;                                   // 0..7
  const int scol = (((lane & 7) ^ srow_in_chunk ^ (wid & 3)) << 3);      // elems

  #define STAGE(buf, kb_)                                                       \
    {                                                                           \
      const int row_ = wid * 8 + srow_in_chunk;                                 \
      gload16((buf) + wid * 1024, Kb + (size_t)((kb_) + row_) * 64 + scol);     \
      gload16((buf) + 8192 + wid * 1024, Vb + (size_t)row_ * 1024 + (kb_) + scol); \
    }

  bf16x8 qf[4];
  #pragma unroll
  for (int c = 0; c < 4; ++c)
    qf[c] = *(const bf16x8*)(Qb + (size_t)(q0 + l31) * 64 + c * 16 + hi * 8);

  // ones B-frag for the row-sum MFMA; persistent zero C-vector for QK^T
  const u32x4 onesu = { 0x3f803f80u, 0x3f803f80u, 0x3f803f80u, 0x3f803f80u };
  const bf16x8 ones = __builtin_bit_cast(bf16x8, onesu);
  f32x16 zv;
  #pragma unroll
  for (int r = 0; r < 16; ++r) zv[r] = 0.f;

  f32x16 o0, o1, sacc;
  #pragma unroll
  for (int r = 0; r < 16; ++r) { o0[r] = 0.f; o1[r] = 0.f; sacc[r] = 0.f; }
  float m = -1e30f;

  const int swz = (((l31 & 7) ^ ((l31 >> 3) & 3)) << 4);   // ds_read swizzle bytes

  STAGE(lds[0], 0);

  for (int kt = 0; kt < 16; ++kt) {
    __syncthreads();   // implicit vmcnt(0): this kt's staged tiles landed; prev readers done
    const char* Kl = lds[kt & 1];
    const char* Vl = lds[kt & 1] + 8192;
    if (kt < 15) STAGE(lds[(kt + 1) & 1], (kt + 1) * 64);   // in flight across compute

    f32x16 s0, s1;
    __builtin_amdgcn_s_setprio(1);
    {
      bf16x8 kf0 = *(const bf16x8*)(Kl + l31 * 128        + ((hi * 16) ^ swz));
      bf16x8 kf1 = *(const bf16x8*)(Kl + (32 + l31) * 128 + ((hi * 16) ^ swz));
      s0 = MFMA32(kf0, qf[0], zv);   // S[k][q]: row=k, col=q=lane&31
      s1 = MFMA32(kf1, qf[0], zv);
    }
    #pragma unroll
    for (int c = 1; c < 4; ++c) {
      bf16x8 kf0 = *(const bf16x8*)(Kl + l31 * 128        + ((c * 32 + hi * 16) ^ swz));
      bf16x8 kf1 = *(const bf16x8*)(Kl + (32 + l31) * 128 + ((c * 32 + hi * 16) ^ swz));
      s0 = MFMA32(kf0, qf[c], s0);
      s1 = MFMA32(kf1, qf[c], s1);
    }
    __builtin_amdgcn_s_setprio(0);
    // full 64-k row max for this lane's q: max3-shaped tree (v_max3_f32, T17)
    float p0 = max3f(s0[0],  s0[1],  s0[2]);
    float p1 = max3f(s0[3],  s0[4],  s0[5]);
    float p2 = max3f(s0[6],  s0[7],  s0[8]);
    float p3 = max3f(s0[9],  s0[10], s0[11]);
    float p4 = max3f(s0[12], s0[13], s0[14]);
    float q1_ = max3f(s1[0],  s1[1],  s1[2]);
    float q2_ = max3f(s1[3],  s1[4],  s1[5]);
    float q3_ = max3f(s1[6],  s1[7],  s1[8]);
    float q4_ = max3f(s1[9],  s1[10], s1[11]);
    float q5_ = max3f(s1[12], s1[13], s1[14]);
    float ta = max3f(p0, p1, p2);
    float tb = max3f(p3, p4, s0[15]);
    float tc = max3f(q1_, q2_, q3_);
    float td = max3f(q4_, q5_, s1[15]);
    float pm = fmaxf(fmaxf(ta, tb), fmaxf(tc, td));
    pm = fmaxf(pm, __shfl_xor(pm, 32, 64));
    const float pmx = pm * ascale;
    if (__any((int)(pmx > m + 8.0f))) {    // rare: rescale path
      const float mnew = fmaxf(m, pmx);
      const float a = exp2f(m - mnew);
      m = mnew;
      #pragma unroll
      for (int r = 0; r < 16; ++r) {
        const float ab = __shfl(a, (r & 3) + 8 * (r >> 2) + 4 * hi, 64);
        o0[r] *= ab; o1[r] *= ab; sacc[r] *= ab;
      }
    }
    const float nm = -m;
    #pragma unroll
    for (int r = 0; r < 16; ++r) {
      s0[r] = exp2f(fmaf(s0[r], ascale, nm));
      s1[r] = exp2f(fmaf(s1[r], ascale, nm));
    }
    // in-register P -> A-frag redistribution (v_cvt_pk_bf16_f32 + permlane32_swap)
    unsigned a0 = pack2(s0[0], s0[1]),   b0 = pack2(s0[4], s0[5]);
    unsigned a1 = pack2(s0[2], s0[3]),   b1 = pack2(s0[6], s0[7]);
    unsigned a2 = pack2(s0[8], s0[9]),   b2 = pack2(s0[12], s0[13]);
    unsigned a3 = pack2(s0[10], s0[11]), b3 = pack2(s0[14], s0[15]);
    unsigned c0 = pack2(s1[0], s1[1]),   d0 = pack2(s1[4], s1[5]);
    unsigned c1 = pack2(s1[2], s1[3]),   d1 = pack2(s1[6], s1[7]);
    unsigned c2 = pack2(s1[8], s1[9]),   d2 = pack2(s1[12], s1[13]);
    unsigned c3 = pack2(s1[10], s1[11]), d3 = pack2(s1[14], s1[15]);
    pswap(a0, b0); pswap(a1, b1); pswap(a2, b2); pswap(a3, b3);
    pswap(c0, d0); pswap(c1, d1); pswap(c2, d2); pswap(c3, d3);
    bf16x8 pfrag[4];
    pfrag[0] = __builtin_bit_cast(bf16x8, (u32x4){a0, a1, b0, b1});
    pfrag[1] = __builtin_bit_cast(bf16x8, (u32x4){a2, a3, b2, b3});
    pfrag[2] = __builtin_bit_cast(bf16x8, (u32x4){c0, c1, d0, d1});
    pfrag[3] = __builtin_bit_cast(bf16x8, (u32x4){c2, c3, d2, d3});
    // PV + row-sum from LDS V tile (same swizzle); sacc layout == o layout
    __builtin_amdgcn_s_setprio(1);
    #pragma unroll
    for (int c = 0; c < 4; ++c) {
      bf16x8 v0 = *(const bf16x8*)(Vl + l31 * 128        + ((c * 32 + hi * 16) ^ swz));
      bf16x8 v1 = *(const bf16x8*)(Vl + (32 + l31) * 128 + ((c * 32 + hi * 16) ^ swz));
      o0 = MFMA32(pfrag[c], v0, o0);
      o1 = MFMA32(pfrag[c], v1, o1);
      sacc = MFMA32(pfrag[c], ones, sacc);
    }
    __builtin_amdgcn_s_setprio(0);
  }
  #undef STAGE

  const int bb = bh >> 4, hh = bh & 15;
  #pragma unroll
  for (int r = 0; r < 16; ++r) {
    const int crow = (r & 3) + 8 * (r >> 2) + 4 * hi;
    const float lb = 1.0f / sacc[r];
    const int srow = q0 + crow;
    AO[(size_t)(bb * 1024 + srow) * 1024 + hh * 64 + l31]      = (__bf16)(o0[r] * lb);
    AO[(size_t)(bb * 1024 + srow) * 1024 + hh * 64 + 32 + l31] = (__bf16)(o1[r] * lb);
  }
}

// ---------------- launch ----------------
extern "C" void kernel_launch(void* const* d_in, const int* in_sizes, int n_in,
                              void* d_out, int out_size, void* d_ws, size_t ws_size,
                              hipStream_t stream)
{
  const float* x        = (const float*)d_in[0];
  const float* cb0      = (const float*)d_in[1];
  const float* cb1      = (const float*)d_in[2];
  const float* cb2      = (const float*)d_in[3];
  const float* cb3      = (const float*)d_in[4];
  const int* codes_qkv  = (const int*)d_in[5];
  const int* codes_out  = (const int*)d_in[6];
  const int* codes_fc1  = (const int*)d_in[7];
  const int* codes_fc2  = (const int*)d_in[8];
  const float* b_out    = (const float*)d_in[9];
  const float* b_fc1    = (const float*)d_in[10];
  const float* b_fc2    = (const float*)d_in[11];
  const float* ln1_w    = (const float*)d_in[12];
  const float* ln1_b    = (const float*)d_in[13];
  const float* ln2_w    = (const float*)d_in[14];
  const float* ln2_b    = (const float*)d_in[15];

  float* Xout = (float*)d_out;           // final fp32 output
  __bf16* ws = (__bf16*)d_ws;
  __bf16* W  = ws;                       // 6144x1024
  __bf16* xn = ws + 6291456;             // 8192x1024
  __bf16* Qb = ws + 14680064;            // (B,H,S,D)
  __bf16* Kb = ws + 23068672;            // (B,H,S,D)
  __bf16* VT = ws + 31457280;            // (B,H,D,S)
  __bf16* AO = ws + 39845888;            // 8192x1024 (also reused as Hb)
  __bf16* Xb = ws + 48234496;            // 8192x1024 bf16 residual stream
  __bf16* Hb = AO;                       // fc1 output aliases AO (disjoint lifetimes)

  for (int i = 0; i < 6; ++i) {
    // LN1 source: layer 0 reads original fp32 x; later layers read bf16 Xb.
    if (i == 0) {
      deq_ln_kernel<true><<<14336, 256, 0, stream>>>(
          W, cb0, cb1, cb2, cb3,
          codes_qkv + (size_t)i * 3072 * 16, codes_out + (size_t)i * 1024 * 16,
          codes_fc1 + (size_t)i * 1024 * 16, codes_fc2 + (size_t)i * 1024 * 16,
          x, ln1_w + i * 1024, ln1_b + i * 1024, xn);
    } else {
      deq_ln_kernel<false><<<14336, 256, 0, stream>>>(
          W, cb0, cb1, cb2, cb3,
          codes_qkv + (size_t)i * 3072 * 16, codes_out + (size_t)i * 1024 * 16,
          codes_fc1 + (size_t)i * 1024 * 16, codes_fc2 + (size_t)i * 1024 * 16,
          Xb, ln1_w + i * 1024, ln1_b + i * 1024, xn);
    }

    gemm_kernel<0><<<dim3(64, 24), 256, 0, stream>>>(
        xn, W, Qb, Kb, VT, nullptr, nullptr, nullptr, nullptr);

    attn_kernel<<<512, 512, 0, stream>>>(Qb, Kb, VT, AO);

    // out-proj residual: layer 0 adds fp32 x (EPI 3); later layers add bf16 Xb (EPI 1).
    if (i == 0) {
      gemm_kernel<3><<<dim3(64, 8), 256, 0, stream>>>(
          AO, W + (size_t)3072 * 1024, nullptr, nullptr, nullptr, nullptr,
          x, Xb, b_out + i * 1024);
    } else {
      gemm_kernel<1><<<dim3(64, 8), 256, 0, stream>>>(
          AO, W + (size_t)3072 * 1024, nullptr, nullptr, nullptr, nullptr,
          Xb, Xb, b_out + i * 1024);
    }

    ln_kernel<<<8192, 256, 0, stream>>>(Xb, ln2_w + i * 1024, ln2_b + i * 1024, xn);

    gemm_kernel<2><<<dim3(64, 8), 256, 0, stream>>>(
        xn, W + (size_t)4096 * 1024, nullptr, nullptr, nullptr, Hb,
        nullptr, nullptr, b_fc1 + i * 1024);

    // fc2 residual: final layer writes fp32 d_out (EPI 4); else bf16 Xb (EPI 1).
    if (i == 5) {
      gemm_kernel<4><<<dim3(64, 8), 256, 0, stream>>>(
          Hb, W + (size_t)5120 * 1024, nullptr, nullptr, nullptr, nullptr,
          Xb, Xout, b_fc2 + i * 1024);
    } else {
      gemm_kernel<1><<<dim3(64, 8), 256, 0, stream>>>(
          Hb, W + (size_t)5120 * 1024, nullptr, nullptr, nullptr, nullptr,
          Xb, Xb, b_fc2 + i * 1024);
    }
  }
}